// Round 1
// baseline (529.124 us; speedup 1.0000x reference)
//
#include <hip/hip_runtime.h>

#define T_DIM 2048
#define B_DIM 16
#define E_DIM 1024
#define CD    1024
#define NH    16
#define KSZ   31
#define M_DIM 32768
#define LDL   512

typedef unsigned int u32;
typedef unsigned short u16;
typedef __attribute__((ext_vector_type(8))) __bf16 bf16x8;
typedef __attribute__((ext_vector_type(4))) float f32x4;
typedef __attribute__((ext_vector_type(4))) float fvec4;
typedef __attribute__((ext_vector_type(8))) unsigned short us8;
typedef __attribute__((ext_vector_type(4))) unsigned short us4;
typedef __attribute__((ext_vector_type(4))) unsigned int ui4;

__device__ __forceinline__ float bf2f(u16 u) {
  union { float f; u32 i; } c; c.i = ((u32)u) << 16; return c.f;
}
__device__ __forceinline__ u16 f2bf(float f) {
  union { float f; u32 i; } c; c.f = f;
  u32 u = c.i;
  u += 0x7fffu + ((u >> 16) & 1u);   // RNE
  return (u16)(u >> 16);
}

#define GLDS(gp, lp)                                                        \
  __builtin_amdgcn_global_load_lds(                                         \
      (__attribute__((address_space(1))) void*)(gp),                        \
      (__attribute__((address_space(3))) void*)(lp), 16, 0, 0)

// ---------------------------------------------------------------- cvt f32->bf16
__global__ __launch_bounds__(256) void cvt_f32_bf16(const float* __restrict__ src,
                                                    u16* __restrict__ dst, int n4) {
  int i = blockIdx.x * 256 + threadIdx.x;
  int stride = gridDim.x * 256;
  const fvec4* s4 = (const fvec4*)src;
  us4* d4 = (us4*)dst;
  for (; i < n4; i += stride) {
    fvec4 v = s4[i];
    us4 o;
    o[0] = f2bf(v[0]); o[1] = f2bf(v[1]); o[2] = f2bf(v[2]); o[3] = f2bf(v[3]);
    d4[i] = o;
  }
}

// ---------------------------------------------------------------- bf16 MFMA GEMM (B^T layout)
// C[M,N] = A[M,K] * B[N,K]^T + bias.  128x128 tile, BK=32, 4 waves (2x2 of 64x64).
template<int OUT_BF16, int GUARD_N>
__global__ __launch_bounds__(256) void gemm_bt(
    const u16* __restrict__ A, const u16* __restrict__ B,
    const float* __restrict__ bias, void* __restrict__ Cout,
    int N, int K, int ldc, int ntn)
{
  constexpr int BK = 32;
  __shared__ u16 sA[128 * BK];
  __shared__ u16 sB[128 * BK];
  const int tid = threadIdx.x;
  const int lane = tid & 63;
  const int wid = tid >> 6;
  const int bm = (blockIdx.x / ntn) * 128;
  const int bn = (blockIdx.x % ntn) * 128;
  const int wr = (wid >> 1) * 64;
  const int wc = (wid & 1) * 64;

  // staging: thread t covers LDS bytes [t*16, t*16+16) (chunk0) and +4096 (chunk1)
  const int srow = tid >> 2;            // 0..63
  const int skoff = (tid & 3) * 8;      // k element offset
  const u16* gA0 = A + (size_t)(bm + srow) * K + skoff;
  const u16* gA1 = gA0 + (size_t)64 * K;
  int brow0 = bn + srow, brow1 = bn + srow + 64;
  if (GUARD_N) { brow0 = min(brow0, N - 1); brow1 = min(brow1, N - 1); }
  const u16* gB0 = B + (size_t)brow0 * K + skoff;
  const u16* gB1 = B + (size_t)brow1 * K + skoff;

  u16* lA0 = sA + wid * 512;            // wave-uniform LDS bases (bytes wid*1024)
  u16* lA1 = sA + 2048 + wid * 512;
  u16* lB0 = sB + wid * 512;
  u16* lB1 = sB + 2048 + wid * 512;

  f32x4 acc[4][4];
  #pragma unroll
  for (int i = 0; i < 4; i++)
    #pragma unroll
    for (int j = 0; j < 4; j++) acc[i][j] = (f32x4)(0.0f);

  const int fr = lane & 15;
  const int fk = (lane >> 4) * 8;

  for (int k0 = 0; k0 < K; k0 += BK) {
    __syncthreads();
    GLDS(gA0, lA0);
    GLDS(gA1, lA1);
    GLDS(gB0, lB0);
    GLDS(gB1, lB1);
    gA0 += BK; gA1 += BK; gB0 += BK; gB1 += BK;
    __syncthreads();   // compiler drains vmcnt(0) before s_barrier -> LDS ready
    bf16x8 aF[4], bF[4];
    #pragma unroll
    for (int m = 0; m < 4; m++)
      aF[m] = *(const bf16x8*)(sA + (wr + m * 16 + fr) * BK + fk);
    #pragma unroll
    for (int n = 0; n < 4; n++)
      bF[n] = *(const bf16x8*)(sB + (wc + n * 16 + fr) * BK + fk);
    #pragma unroll
    for (int m = 0; m < 4; m++)
      #pragma unroll
      for (int n = 0; n < 4; n++)
        acc[m][n] = __builtin_amdgcn_mfma_f32_16x16x32_bf16(aF[m], bF[n], acc[m][n], 0, 0, 0);
  }

  const int orow = bm + wr + (lane >> 4) * 4;   // C/D: col=lane&15, row=(lane>>4)*4+q
  const int ocol = bn + wc + fr;
  #pragma unroll
  for (int m = 0; m < 4; m++) {
    #pragma unroll
    for (int n = 0; n < 4; n++) {
      #pragma unroll
      for (int q = 0; q < 4; q++) {
        int row = orow + m * 16 + q;
        int col = ocol + n * 16;
        if (!GUARD_N || col < N) {
          float v = acc[m][n][q] + bias[col];
          if (OUT_BF16) ((u16*)Cout)[(size_t)row * ldc + col] = f2bf(v);
          else          ((float*)Cout)[(size_t)row * ldc + col] = v;
        }
      }
    }
  }
}

// ---------------------------------------------------------------- softmax over K=31, in place
__global__ __launch_bounds__(256) void softmax31(float* __restrict__ wsm) {
  int idx = blockIdx.x * 256 + threadIdx.x;   // one per (m, head)
  if (idx >= M_DIM * NH) return;
  int m = idx >> 4;
  int h = idx & 15;
  float* p = wsm + (size_t)m * LDL + h * KSZ;
  float v[KSZ];
  float mx = -1e30f;
  #pragma unroll
  for (int k = 0; k < KSZ; k++) { v[k] = p[k]; mx = fmaxf(mx, v[k]); }
  float s = 0.f;
  #pragma unroll
  for (int k = 0; k < KSZ; k++) { v[k] = __expf(v[k] - mx); s += v[k]; }
  float inv = 1.0f / s;
  #pragma unroll
  for (int k = 0; k < KSZ; k++) p[k] = v[k] * inv;
}

// ---------------------------------------------------------------- dynamic conv
// out[t,b,c] = sum_k w[t,b,h,k] * h1[t+k-30, b, c],  h = c/64.
// block: 128 t-values for one (b, head). thread: 8 channels x 4 consecutive t.
__global__ __launch_bounds__(256) void dconv(const u16* __restrict__ h1,
                                             const float* __restrict__ wsm,
                                             u16* __restrict__ outc)
{
  constexpr int TT = 128, HALO = 30;
  int bid = blockIdx.x;
  int tt = bid & 15;            // T/128 = 16
  int b  = (bid >> 4) & 15;
  int h  = bid >> 8;            // 0..15
  int t0 = tt * TT;
  __shared__ u16 hl[TT + HALO][64];     // 158 x 64 bf16
  __shared__ float wl[TT][36];          // padded stride 36: conflict-free float4 reads
  int tid = threadIdx.x;

  for (int c = tid; c < (TT + HALO) * 8; c += 256) {
    int i = c >> 3, sub = c & 7;
    int tr = t0 - HALO + i;
    ui4 val = (ui4)(0u);
    if (tr >= 0)
      val = *(const ui4*)(h1 + ((size_t)tr * B_DIM + b) * CD + h * 64 + sub * 8);
    *(ui4*)(&hl[i][sub * 8]) = val;
  }
  for (int c = tid; c < TT * KSZ; c += 256) {
    int j = c / KSZ, k = c - j * KSZ;
    wl[j][k] = wsm[((size_t)(t0 + j) * B_DIM + b) * LDL + h * KSZ + k];
  }
  __syncthreads();

  int rb = (tid & 7) * 8;           // channel sub-block
  int tlb = (tid >> 3) * 4;         // 4 consecutive local t per thread

  float hw[4][8];                   // rolling 4-row window (registers)
  #pragma unroll
  for (int j = 0; j < 3; j++) {
    us8 hv = *(const us8*)(&hl[tlb + j][rb]);
    #pragma unroll
    for (int e = 0; e < 8; e++) hw[j][e] = bf2f(hv[e]);
  }
  float acc[4][8];
  #pragma unroll
  for (int dt = 0; dt < 4; dt++)
    #pragma unroll
    for (int e = 0; e < 8; e++) acc[dt][e] = 0.f;

  #pragma unroll
  for (int k4 = 0; k4 < 8; k4++) {
    fvec4 w4[4];
    #pragma unroll
    for (int dt = 0; dt < 4; dt++) w4[dt] = *(const fvec4*)(&wl[tlb + dt][k4 * 4]);
    #pragma unroll
    for (int j = 0; j < 4; j++) {
      const int k = k4 * 4 + j;
      if (k < KSZ) {
        us8 hv = *(const us8*)(&hl[tlb + k + 3][rb]);
        #pragma unroll
        for (int e = 0; e < 8; e++) hw[(k + 3) & 3][e] = bf2f(hv[e]);
        #pragma unroll
        for (int dt = 0; dt < 4; dt++) {
          float w = w4[dt][j];
          #pragma unroll
          for (int e = 0; e < 8; e++) acc[dt][e] += w * hw[(k + dt) & 3][e];
        }
      }
    }
  }
  #pragma unroll
  for (int dt = 0; dt < 4; dt++) {
    us8 o;
    #pragma unroll
    for (int e = 0; e < 8; e++) o[e] = f2bf(acc[dt][e]);
    *(us8*)(outc + ((size_t)(t0 + tlb + dt) * B_DIM + b) * CD + h * 64 + rb) = o;
  }
}

// ---------------------------------------------------------------- residual + LayerNorm, in place on d_out
__global__ __launch_bounds__(256) void ln_res(const float* __restrict__ x,
                                              float* __restrict__ io,
                                              const float* __restrict__ gamma,
                                              const float* __restrict__ beta)
{
  int row = blockIdx.x;
  const fvec4* xr = (const fvec4*)(x + (size_t)row * E_DIM);
  fvec4* yr = (fvec4*)(io + (size_t)row * E_DIM);
  int tid = threadIdx.x;
  fvec4 hv = yr[tid];
  fvec4 xv = xr[tid];
  fvec4 s = hv + xv;
  float sum = s[0] + s[1] + s[2] + s[3];
  float sq  = s[0]*s[0] + s[1]*s[1] + s[2]*s[2] + s[3]*s[3];
  #pragma unroll
  for (int off = 32; off >= 1; off >>= 1) {
    sum += __shfl_xor(sum, off, 64);
    sq  += __shfl_xor(sq, off, 64);
  }
  __shared__ float red[8];
  int lane = tid & 63, wid = tid >> 6;
  if (lane == 0) { red[wid] = sum; red[4 + wid] = sq; }
  __syncthreads();
  sum = red[0] + red[1] + red[2] + red[3];
  sq  = red[4] + red[5] + red[6] + red[7];
  float mean = sum * (1.0f / E_DIM);
  float var  = sq * (1.0f / E_DIM) - mean * mean;
  float rstd = rsqrtf(var + 1e-5f);
  fvec4 g = ((const fvec4*)gamma)[tid];
  fvec4 be = ((const fvec4*)beta)[tid];
  fvec4 o;
  #pragma unroll
  for (int e = 0; e < 4; e++) o[e] = (s[e] - mean) * rstd * g[e] + be[e];
  yr[tid] = o;
}

// ---------------------------------------------------------------- launcher
extern "C" void kernel_launch(void* const* d_in, const int* in_sizes, int n_in,
                              void* d_out, int out_size, void* d_ws, size_t ws_size,
                              hipStream_t stream)
{
  const float* x     = (const float*)d_in[0];
  const float* w1    = (const float*)d_in[1];
  const float* b1    = (const float*)d_in[2];
  const float* ww    = (const float*)d_in[3];
  const float* bw    = (const float*)d_in[4];
  const float* w2    = (const float*)d_in[5];
  const float* b2    = (const float*)d_in[6];
  const float* gamma = (const float*)d_in[7];
  const float* beta  = (const float*)d_in[8];
  float* out = (float*)d_out;

  char* ws = (char*)d_ws;
  u16*   xb   = (u16*)(ws);                          // 64 MB (reused as conv out)
  u16*   h1   = (u16*)(ws + ((size_t)64 << 20));     // 64 MB
  float* lg   = (float*)(ws + ((size_t)128 << 20));  // 64 MB logits -> softmax (stride 512)
  u16*   w1b  = (u16*)(ws + ((size_t)192 << 20));    // 2 MB
  u16*   w2b  = (u16*)(ws + ((size_t)194 << 20));    // 2 MB
  u16*   wwb  = (u16*)(ws + ((size_t)196 << 20));    // ~1 MB
  u16*   convout = xb;

  cvt_f32_bf16<<<8192, 256, 0, stream>>>(x,  xb,  (T_DIM * B_DIM * E_DIM) / 4);
  cvt_f32_bf16<<<1024, 256, 0, stream>>>(w1, w1b, (CD * E_DIM) / 4);
  cvt_f32_bf16<<<1024, 256, 0, stream>>>(w2, w2b, (E_DIM * CD) / 4);
  cvt_f32_bf16<<<512,  256, 0, stream>>>(ww, wwb, (NH * KSZ * CD) / 4);

  // h1 = x @ w1^T + b1   (bf16 out)
  gemm_bt<1, 0><<<2048, 256, 0, stream>>>(xb, w1b, b1, h1, CD, E_DIM, CD, 8);
  // logits = h1 @ ww^T + bw   (f32 out, ldc=512, N=496 guarded)
  gemm_bt<0, 1><<<1024, 256, 0, stream>>>(h1, wwb, bw, lg, NH * KSZ, CD, LDL, 4);
  softmax31<<<2048, 256, 0, stream>>>(lg);
  dconv<<<4096, 256, 0, stream>>>(h1, lg, convout);
  // d_out = conv @ w2^T + b2   (f32)
  gemm_bt<0, 0><<<2048, 256, 0, stream>>>(convout, w2b, b2, out, E_DIM, CD, E_DIM, 8);
  ln_res<<<32768, 256, 0, stream>>>(x, out, gamma, beta);
}

// Round 2
// 514.919 us; speedup vs baseline: 1.0276x; 1.0276x over previous
//
#include <hip/hip_runtime.h>

#define T_DIM 2048
#define B_DIM 16
#define E_DIM 1024
#define CD    1024
#define NH    16
#define KSZ   31
#define M_DIM 32768

typedef unsigned int u32;
typedef unsigned short u16;
typedef __attribute__((ext_vector_type(8))) __bf16 bf16x8;
typedef __attribute__((ext_vector_type(4))) float f32x4;
typedef __attribute__((ext_vector_type(4))) float fvec4;
typedef __attribute__((ext_vector_type(8))) unsigned short us8;
typedef __attribute__((ext_vector_type(4))) unsigned short us4;
typedef __attribute__((ext_vector_type(4))) unsigned int ui4;

__device__ __forceinline__ float bf2f(u16 u) {
  union { float f; u32 i; } c; c.i = ((u32)u) << 16; return c.f;
}
__device__ __forceinline__ u16 f2bf(float f) {
  union { float f; u32 i; } c; c.f = f;
  u32 u = c.i;
  u += 0x7fffu + ((u >> 16) & 1u);   // RNE
  return (u16)(u >> 16);
}

#define GLDS(gp, lp)                                                        \
  __builtin_amdgcn_global_load_lds(                                         \
      (__attribute__((address_space(1))) void*)(gp),                        \
      (__attribute__((address_space(3))) void*)(lp), 16, 0, 0)

// ---------------------------------------------------------------- cvt f32->bf16
__global__ __launch_bounds__(256) void cvt_f32_bf16(const float* __restrict__ src,
                                                    u16* __restrict__ dst, int n4) {
  int i = blockIdx.x * 256 + threadIdx.x;
  int stride = gridDim.x * 256;
  const fvec4* s4 = (const fvec4*)src;
  us4* d4 = (us4*)dst;
  for (; i < n4; i += stride) {
    fvec4 v = s4[i];
    us4 o;
    o[0] = f2bf(v[0]); o[1] = f2bf(v[1]); o[2] = f2bf(v[2]); o[3] = f2bf(v[3]);
    d4[i] = o;
  }
}

// ---------------------------------------------------------------- bf16 MFMA GEMM (B^T layout)
// C[M,N] = A[M,K] * B[N,K]^T + bias.  128x128 tile, BK=32, 4 waves (2x2 of 64x64).
// OUT_MODE: 0 = f32 row-major (ldc), 1 = bf16 row-major (ldc), 2 = wt[b][h][t][32] f32 layout.
template<int OUT_MODE, int GUARD_N>
__global__ __launch_bounds__(256) void gemm_bt(
    const u16* __restrict__ A, const u16* __restrict__ B,
    const float* __restrict__ bias, void* __restrict__ Cout,
    int N, int K, int ldc, int ntn)
{
  constexpr int BK = 32;
  __shared__ u16 sA[128 * BK];
  __shared__ u16 sB[128 * BK];
  const int tid = threadIdx.x;
  const int lane = tid & 63;
  const int wid = tid >> 6;
  const int bm = (blockIdx.x / ntn) * 128;
  const int bn = (blockIdx.x % ntn) * 128;
  const int wr = (wid >> 1) * 64;
  const int wc = (wid & 1) * 64;

  const int srow = tid >> 2;            // 0..63
  const int skoff = (tid & 3) * 8;      // k element offset
  const u16* gA0 = A + (size_t)(bm + srow) * K + skoff;
  const u16* gA1 = gA0 + (size_t)64 * K;
  int brow0 = bn + srow, brow1 = bn + srow + 64;
  if (GUARD_N) { brow0 = min(brow0, N - 1); brow1 = min(brow1, N - 1); }
  const u16* gB0 = B + (size_t)brow0 * K + skoff;
  const u16* gB1 = B + (size_t)brow1 * K + skoff;

  u16* lA0 = sA + wid * 512;            // wave-uniform LDS bases
  u16* lA1 = sA + 2048 + wid * 512;
  u16* lB0 = sB + wid * 512;
  u16* lB1 = sB + 2048 + wid * 512;

  f32x4 acc[4][4];
  #pragma unroll
  for (int i = 0; i < 4; i++)
    #pragma unroll
    for (int j = 0; j < 4; j++) acc[i][j] = (f32x4)(0.0f);

  const int fr = lane & 15;
  const int fk = (lane >> 4) * 8;

  for (int k0 = 0; k0 < K; k0 += BK) {
    __syncthreads();
    GLDS(gA0, lA0);
    GLDS(gA1, lA1);
    GLDS(gB0, lB0);
    GLDS(gB1, lB1);
    gA0 += BK; gA1 += BK; gB0 += BK; gB1 += BK;
    __syncthreads();
    bf16x8 aF[4], bF[4];
    #pragma unroll
    for (int m = 0; m < 4; m++)
      aF[m] = *(const bf16x8*)(sA + (wr + m * 16 + fr) * BK + fk);
    #pragma unroll
    for (int n = 0; n < 4; n++)
      bF[n] = *(const bf16x8*)(sB + (wc + n * 16 + fr) * BK + fk);
    #pragma unroll
    for (int m = 0; m < 4; m++)
      #pragma unroll
      for (int n = 0; n < 4; n++)
        acc[m][n] = __builtin_amdgcn_mfma_f32_16x16x32_bf16(aF[m], bF[n], acc[m][n], 0, 0, 0);
  }

  const int orow = bm + wr + (lane >> 4) * 4;   // C/D: col=lane&15, row=(lane>>4)*4+q
  const int ocol = bn + wc + fr;
  #pragma unroll
  for (int m = 0; m < 4; m++) {
    #pragma unroll
    for (int n = 0; n < 4; n++) {
      #pragma unroll
      for (int q = 0; q < 4; q++) {
        int row = orow + m * 16 + q;
        int col = ocol + n * 16;
        if (!GUARD_N || col < N) {
          float v = acc[m][n][q] + bias[col];
          if (OUT_MODE == 0) {
            ((float*)Cout)[(size_t)row * ldc + col] = v;
          } else if (OUT_MODE == 1) {
            ((u16*)Cout)[(size_t)row * ldc + col] = f2bf(v);
          } else {
            int hh = col / 31, kk = col - hh * 31;      // compile-time magic div
            int t = row >> 4, bb = row & 15;
            ((float*)Cout)[((size_t)((bb * NH + hh) * T_DIM + t)) * 32 + kk] = v;
          }
        }
      }
    }
  }
}

// ---------------------------------------------------------------- softmax over K=31, in place on wt rows
__global__ __launch_bounds__(256) void softmax31(float* __restrict__ wt) {
  int idx = blockIdx.x * 256 + threadIdx.x;   // one row (b,h,t) per thread
  float* p = wt + (size_t)idx * 32;
  float v[KSZ];
  float mx = -1e30f;
  #pragma unroll
  for (int k = 0; k < KSZ; k++) { v[k] = p[k]; mx = fmaxf(mx, v[k]); }
  float s = 0.f;
  #pragma unroll
  for (int k = 0; k < KSZ; k++) { v[k] = __expf(v[k] - mx); s += v[k]; }
  float inv = 1.0f / s;
  #pragma unroll
  for (int k = 0; k < KSZ; k++) p[k] = v[k] * inv;
}

// ---------------------------------------------------------------- dynamic conv
// out[t,b,c] = sum_k w[t,b,h,k] * h1[t+k-30, b, c],  h = c/64.
// block: 128 t-values for one (b, head). thread: 8 channels x 4 consecutive t.
// w read straight from global wt[b][h][t][32] (L1 broadcast, 16 KB unique/block).
__global__ __launch_bounds__(256) void dconv(const u16* __restrict__ h1,
                                             const float* __restrict__ wt,
                                             u16* __restrict__ outc)
{
  constexpr int TT = 128, HALO = 30, SH = 72;   // 144 B row stride: 4-way (not 8-way) conflicts
  int bid = blockIdx.x;
  int tt = bid & 15;            // T/128 = 16
  int b  = (bid >> 4) & 15;
  int h  = bid >> 8;            // 0..15
  int t0 = tt * TT;
  __shared__ u16 hl[(TT + HALO) * SH];   // 158 x 72 bf16 = 22.75 KB
  int tid = threadIdx.x;

  for (int c = tid; c < (TT + HALO) * 8; c += 256) {
    int i = c >> 3, sub = c & 7;
    int tr = t0 - HALO + i;
    ui4 val = (ui4)(0u);
    if (tr >= 0)
      val = *(const ui4*)(h1 + ((size_t)tr * B_DIM + b) * CD + h * 64 + sub * 8);
    *(ui4*)(&hl[i * SH + sub * 8]) = val;
  }
  __syncthreads();

  int rb = (tid & 7) * 8;           // channel sub-block
  int tlb = (tid >> 3) * 4;         // 4 consecutive local t per thread
  const float* wp = wt + ((size_t)((b * NH + h) * T_DIM + t0 + tlb)) * 32;

  float hw[4][8];                   // rolling 4-row window (registers)
  #pragma unroll
  for (int j = 0; j < 3; j++) {
    us8 hv = *(const us8*)(&hl[(tlb + j) * SH + rb]);
    #pragma unroll
    for (int e = 0; e < 8; e++) hw[j][e] = bf2f(hv[e]);
  }
  float acc[4][8];
  #pragma unroll
  for (int dt = 0; dt < 4; dt++)
    #pragma unroll
    for (int e = 0; e < 8; e++) acc[dt][e] = 0.f;

  #pragma unroll
  for (int k4 = 0; k4 < 8; k4++) {
    f32x4 w4[4];
    #pragma unroll
    for (int dt = 0; dt < 4; dt++) w4[dt] = *(const f32x4*)(wp + dt * 32 + k4 * 4);
    #pragma unroll
    for (int j = 0; j < 4; j++) {
      const int k = k4 * 4 + j;
      if (k < KSZ) {
        us8 hv = *(const us8*)(&hl[(tlb + k + 3) * SH + rb]);
        #pragma unroll
        for (int e = 0; e < 8; e++) hw[(k + 3) & 3][e] = bf2f(hv[e]);
        #pragma unroll
        for (int dt = 0; dt < 4; dt++) {
          float w = w4[dt][j];
          #pragma unroll
          for (int e = 0; e < 8; e++) acc[dt][e] += w * hw[(k + dt) & 3][e];
        }
      }
    }
  }
  #pragma unroll
  for (int dt = 0; dt < 4; dt++) {
    us8 o;
    #pragma unroll
    for (int e = 0; e < 8; e++) o[e] = f2bf(acc[dt][e]);
    *(us8*)(outc + ((size_t)(t0 + tlb + dt) * B_DIM + b) * CD + h * 64 + rb) = o;
  }
}

// ---------------------------------------------------------------- residual + LayerNorm (bf16 h + f32 x -> f32 out)
__global__ __launch_bounds__(256) void ln_res(const float* __restrict__ x,
                                              const u16* __restrict__ hb,
                                              float* __restrict__ out,
                                              const float* __restrict__ gamma,
                                              const float* __restrict__ beta)
{
  int row = blockIdx.x;
  const fvec4* xr = (const fvec4*)(x + (size_t)row * E_DIM);
  const us4* hr = (const us4*)(hb + (size_t)row * E_DIM);
  fvec4* yr = (fvec4*)(out + (size_t)row * E_DIM);
  int tid = threadIdx.x;
  us4 hv = hr[tid];
  fvec4 xv = xr[tid];
  fvec4 s;
  #pragma unroll
  for (int e = 0; e < 4; e++) s[e] = xv[e] + bf2f(hv[e]);
  float sum = s[0] + s[1] + s[2] + s[3];
  float sq  = s[0]*s[0] + s[1]*s[1] + s[2]*s[2] + s[3]*s[3];
  #pragma unroll
  for (int off = 32; off >= 1; off >>= 1) {
    sum += __shfl_xor(sum, off, 64);
    sq  += __shfl_xor(sq, off, 64);
  }
  __shared__ float red[8];
  int lane = tid & 63, wid = tid >> 6;
  if (lane == 0) { red[wid] = sum; red[4 + wid] = sq; }
  __syncthreads();
  sum = red[0] + red[1] + red[2] + red[3];
  sq  = red[4] + red[5] + red[6] + red[7];
  float mean = sum * (1.0f / E_DIM);
  float var  = sq * (1.0f / E_DIM) - mean * mean;
  float rstd = rsqrtf(var + 1e-5f);
  fvec4 g = ((const fvec4*)gamma)[tid];
  fvec4 be = ((const fvec4*)beta)[tid];
  fvec4 o;
  #pragma unroll
  for (int e = 0; e < 4; e++) o[e] = (s[e] - mean) * rstd * g[e] + be[e];
  yr[tid] = o;
}

// ---------------------------------------------------------------- launcher
extern "C" void kernel_launch(void* const* d_in, const int* in_sizes, int n_in,
                              void* d_out, int out_size, void* d_ws, size_t ws_size,
                              hipStream_t stream)
{
  const float* x     = (const float*)d_in[0];
  const float* w1    = (const float*)d_in[1];
  const float* b1    = (const float*)d_in[2];
  const float* ww    = (const float*)d_in[3];
  const float* bw    = (const float*)d_in[4];
  const float* w2    = (const float*)d_in[5];
  const float* b2    = (const float*)d_in[6];
  const float* gamma = (const float*)d_in[7];
  const float* beta  = (const float*)d_in[8];
  float* out = (float*)d_out;

  char* ws = (char*)d_ws;
  u16*   xb   = (u16*)(ws);                          // 64 MB  (bf16 x; reused as conv out)
  u16*   h1   = (u16*)(ws + ((size_t)64 << 20));     // 64 MB  (bf16 h1; reused as bf16 h2)
  float* wt   = (float*)(ws + ((size_t)128 << 20));  // 64 MB  wt[b][h][t][32] f32
  u16*   w1b  = (u16*)(ws + ((size_t)192 << 20));    // 2 MB
  u16*   w2b  = (u16*)(ws + ((size_t)194 << 20));    // 2 MB
  u16*   wwb  = (u16*)(ws + ((size_t)196 << 20));    // ~1 MB
  u16*   convout = xb;
  u16*   h2b = h1;

  cvt_f32_bf16<<<8192, 256, 0, stream>>>(x,  xb,  (T_DIM * B_DIM * E_DIM) / 4);
  cvt_f32_bf16<<<1024, 256, 0, stream>>>(w1, w1b, (CD * E_DIM) / 4);
  cvt_f32_bf16<<<1024, 256, 0, stream>>>(w2, w2b, (E_DIM * CD) / 4);
  cvt_f32_bf16<<<512,  256, 0, stream>>>(ww, wwb, (NH * KSZ * CD) / 4);

  // h1 = x @ w1^T + b1   (bf16 out)
  gemm_bt<1, 0><<<2048, 256, 0, stream>>>(xb, w1b, b1, h1, CD, E_DIM, CD, 8);
  // wt[b][h][t][k] = (h1 @ ww^T + bw)   (f32, scattered epilogue, N=496 guarded)
  gemm_bt<2, 1><<<1024, 256, 0, stream>>>(h1, wwb, bw, wt, NH * KSZ, CD, 0, 4);
  softmax31<<<2048, 256, 0, stream>>>(wt);
  dconv<<<4096, 256, 0, stream>>>(h1, wt, convout);
  // h2 = conv @ w2^T + b2   (bf16)
  gemm_bt<1, 0><<<2048, 256, 0, stream>>>(convout, w2b, b2, h2b, E_DIM, CD, E_DIM, 8);
  ln_res<<<32768, 256, 0, stream>>>(x, h2b, out, gamma, beta);
}